// Round 2
// baseline (656.534 us; speedup 1.0000x reference)
//
#include <hip/hip_runtime.h>
#include <math.h>

// Problem constants
#define Bb 2
#define Hh 128
#define Ww 128
#define DM 96
#define DE 192
#define Ns 16
#define Rr 6
#define NPOS (Bb*Hh*Ww)          // 32768
#define NC 38                    // R + 2N per direction
#define PBLK 16                  // positions per thread in GEMM kernels

__device__ __forceinline__ float silu_f(float v) {
    return v / (1.f + __expf(-v));
}

// K1: in_proj GEMM. out channels 0..191 -> xp, 192..383 -> silu -> zs
// K-chunked register weights: wr[32] live per chunk (no spill), acc[16] across.
__global__ __launch_bounds__(256) void k_inproj(const float* __restrict__ x,
                                                const float* __restrict__ w,   // (384,96)
                                                float* __restrict__ xp,
                                                float* __restrict__ zs) {
    int task = blockIdx.x * 256 + threadIdx.x;       // 384 * (NPOS/16)
    int c  = task % 384;
    int pb = task / 384;
    int p0 = pb * PBLK;
    const float* wrow = w + (size_t)c * 96;
    float acc[PBLK];
#pragma unroll
    for (int i = 0; i < PBLK; ++i) acc[i] = 0.f;
#pragma unroll 1
    for (int kc = 0; kc < 96; kc += 32) {
        float wr[32];
#pragma unroll
        for (int j = 0; j < 32; j += 4) {
            float4 q = *(const float4*)(wrow + kc + j);
            wr[j] = q.x; wr[j+1] = q.y; wr[j+2] = q.z; wr[j+3] = q.w;
        }
#pragma unroll
        for (int pi = 0; pi < PBLK; ++pi) {
            const float* xr = x + (size_t)(p0 + pi) * 96 + kc;
            float a0 = 0.f, a1 = 0.f, a2 = 0.f, a3 = 0.f;
#pragma unroll
            for (int j = 0; j < 32; j += 4) {
                float4 q = *(const float4*)(xr + j);
                a0 = fmaf(wr[j],   q.x, a0);
                a1 = fmaf(wr[j+1], q.y, a1);
                a2 = fmaf(wr[j+2], q.z, a2);
                a3 = fmaf(wr[j+3], q.w, a3);
            }
            acc[pi] += (a0 + a1) + (a2 + a3);
        }
    }
    if (c < DE) {
#pragma unroll
        for (int pi = 0; pi < PBLK; ++pi)
            xp[(size_t)(p0 + pi) * DE + c] = acc[pi];
    } else {
#pragma unroll
        for (int pi = 0; pi < PBLK; ++pi)
            zs[(size_t)(p0 + pi) * DE + (c - DE)] = silu_f(acc[pi]);
    }
}

// K2: depthwise 3x3 conv (pad 1) + bias + silu, channel-last layout.
__global__ __launch_bounds__(256) void k_conv(const float* __restrict__ xp,
                                              const float* __restrict__ cw,   // (192,9)
                                              const float* __restrict__ cb,
                                              float* __restrict__ xc) {
    int t = blockIdx.x * 256 + threadIdx.x;          // NPOS * 48
    int dq  = t % 48;
    int pos = t / 48;
    int ww = pos % Ww;
    int hh = (pos / Ww) % Hh;
    int bb = pos / (Hh * Ww);
    int d0 = dq * 4;
    float wgt[4][9];
#pragma unroll
    for (int cc = 0; cc < 4; ++cc)
#pragma unroll
        for (int i = 0; i < 9; ++i) wgt[cc][i] = cw[(size_t)(d0 + cc) * 9 + i];
    float a0 = 0.f, a1 = 0.f, a2 = 0.f, a3 = 0.f;
#pragma unroll
    for (int kh = 0; kh < 3; ++kh) {
        int h2 = hh + kh - 1;
        if (h2 < 0 || h2 >= Hh) continue;
#pragma unroll
        for (int kw = 0; kw < 3; ++kw) {
            int w2 = ww + kw - 1;
            if (w2 < 0 || w2 >= Ww) continue;
            const float4 q = *(const float4*)(xp + ((size_t)((bb * Hh + h2) * Ww + w2)) * DE + d0);
            int i = kh * 3 + kw;
            a0 = fmaf(wgt[0][i], q.x, a0);
            a1 = fmaf(wgt[1][i], q.y, a1);
            a2 = fmaf(wgt[2][i], q.z, a2);
            a3 = fmaf(wgt[3][i], q.w, a3);
        }
    }
    float4 r;
    r.x = silu_f(a0 + cb[d0]);
    r.y = silu_f(a1 + cb[d0+1]);
    r.z = silu_f(a2 + cb[d0+2]);
    r.w = silu_f(a3 + cb[d0+3]);
    *(float4*)(xc + (size_t)pos * DE + d0) = r;
}

// K3: x_proj: per position, 76 outputs (2 dirs x 38), dot over 192 channels.
__global__ __launch_bounds__(256) void k_xproj(const float* __restrict__ xc,
                                               const float* __restrict__ xpw,  // (2,38,192)
                                               float* __restrict__ P) {
    int task = blockIdx.x * 256 + threadIdx.x;       // 76 * (NPOS/16)
    int c  = task % (2 * NC);
    int pb = task / (2 * NC);
    int p0 = pb * PBLK;
    const float* wrow = xpw + (size_t)c * DE;
    float acc[PBLK];
#pragma unroll
    for (int i = 0; i < PBLK; ++i) acc[i] = 0.f;
#pragma unroll 1
    for (int kc = 0; kc < DE; kc += 32) {
        float wr[32];
#pragma unroll
        for (int j = 0; j < 32; j += 4) {
            float4 q = *(const float4*)(wrow + kc + j);
            wr[j] = q.x; wr[j+1] = q.y; wr[j+2] = q.z; wr[j+3] = q.w;
        }
#pragma unroll
        for (int pi = 0; pi < PBLK; ++pi) {
            const float* xr = xc + (size_t)(p0 + pi) * DE + kc;
            float a0 = 0.f, a1 = 0.f, a2 = 0.f, a3 = 0.f;
#pragma unroll
            for (int j = 0; j < 32; j += 4) {
                float4 q = *(const float4*)(xr + j);
                a0 = fmaf(wr[j],   q.x, a0);
                a1 = fmaf(wr[j+1], q.y, a1);
                a2 = fmaf(wr[j+2], q.z, a2);
                a3 = fmaf(wr[j+3], q.w, a3);
            }
            acc[pi] += (a0 + a1) + (a2 + a3);
        }
    }
#pragma unroll
    for (int pi = 0; pi < PBLK; ++pi) P[(size_t)(p0 + pi) * (2 * NC) + c] = acc[pi];
}

// K4: selective scan. One block per (b,w,k): 512 blocks x 192 threads.
// Thread = channel d; 16-state recurrence in registers; writes per-direction
// output at the CONSUMED spatial h so the direction merge is a plain add.
__global__ __launch_bounds__(192) void k_scan(const float* __restrict__ xc,
                                              const float* __restrict__ P,
                                              const float* __restrict__ dtw,   // (2,192,6)
                                              const float* __restrict__ dtb,   // (2,192)
                                              const float* __restrict__ A_logs,// (384,16)
                                              const float* __restrict__ Ds,
                                              float* __restrict__ yb) {        // (pos,2,192)
    int blk = blockIdx.x;
    int k  = blk & 1;
    int bw = blk >> 1;
    int ww = bw % Ww, bb = bw / Ww;
    int d  = threadIdx.x;
    int kd = k * DE + d;

    float As[Ns];
#pragma unroll
    for (int n = 0; n < Ns; ++n) As[n] = -__expf(A_logs[(size_t)kd * Ns + n]);
    float wdt[Rr];
#pragma unroll
    for (int r = 0; r < Rr; ++r) wdt[r] = dtw[(size_t)kd * Rr + r];
    float bias = dtb[kd];
    float Dv   = Ds[kd];

    float hst[Ns];
#pragma unroll
    for (int n = 0; n < Ns; ++n) hst[n] = 0.f;

    for (int l = 0; l < Hh; ++l) {
        int hh = k ? (Hh - 1 - l) : l;
        size_t pos = (size_t)((bb * Hh + hh) * Ww + ww);
        float u = xc[pos * DE + d];
        const float* pr = P + pos * (2 * NC) + k * NC;
        float dtr = bias;
#pragma unroll
        for (int r = 0; r < Rr; ++r) dtr = fmaf(wdt[r], pr[r], dtr);
        float delta = (dtr > 20.f) ? dtr : log1pf(__expf(dtr));
        float du = delta * u;
        float y = 0.f;
#pragma unroll
        for (int n = 0; n < Ns; ++n) {
            float dA = __expf(delta * As[n]);
            hst[n] = fmaf(dA, hst[n], du * pr[Rr + n]);
            y = fmaf(hst[n], pr[Rr + Ns + n], y);
        }
        yb[(pos * 2 + k) * DE + d] = y + Dv * u;
    }
}

// K5: merge directions + LayerNorm(192) + gate with silu(z). Wave per position.
__global__ __launch_bounds__(256) void k_lngate(const float* __restrict__ yb,
                                                const float* __restrict__ zs,
                                                const float* __restrict__ gamma,
                                                const float* __restrict__ beta,
                                                float* __restrict__ gated) {
    int wv   = threadIdx.x >> 6;
    int lane = threadIdx.x & 63;
    size_t pos = (size_t)blockIdx.x * 4 + wv;
    const float* yr = yb + pos * (2 * DE);
    float v[3];
#pragma unroll
    for (int i = 0; i < 3; ++i) {
        int dd = lane + 64 * i;
        v[i] = yr[dd] + yr[DE + dd];
    }
    float s  = v[0] + v[1] + v[2];
    float s2 = v[0]*v[0] + v[1]*v[1] + v[2]*v[2];
#pragma unroll
    for (int off = 32; off; off >>= 1) {
        s  += __shfl_xor(s, off);
        s2 += __shfl_xor(s2, off);
    }
    float mu   = s * (1.f / DE);
    float var  = s2 * (1.f / DE) - mu * mu;
    float rstd = rsqrtf(var + 1e-5f);
#pragma unroll
    for (int i = 0; i < 3; ++i) {
        int dd = lane + 64 * i;
        float g = (v[i] - mu) * rstd * gamma[dd] + beta[dd];
        gated[pos * DE + dd] = g * zs[pos * DE + dd];
    }
}

// K6: out_proj GEMM: 96 outputs, K=192.
__global__ __launch_bounds__(256) void k_outproj(const float* __restrict__ gated,
                                                 const float* __restrict__ wo,  // (96,192)
                                                 float* __restrict__ out) {
    int task = blockIdx.x * 256 + threadIdx.x;       // 96 * (NPOS/16)
    int c  = task % DM;
    int pb = task / DM;
    int p0 = pb * PBLK;
    const float* wrow = wo + (size_t)c * DE;
    float acc[PBLK];
#pragma unroll
    for (int i = 0; i < PBLK; ++i) acc[i] = 0.f;
#pragma unroll 1
    for (int kc = 0; kc < DE; kc += 32) {
        float wr[32];
#pragma unroll
        for (int j = 0; j < 32; j += 4) {
            float4 q = *(const float4*)(wrow + kc + j);
            wr[j] = q.x; wr[j+1] = q.y; wr[j+2] = q.z; wr[j+3] = q.w;
        }
#pragma unroll
        for (int pi = 0; pi < PBLK; ++pi) {
            const float* xr = gated + (size_t)(p0 + pi) * DE + kc;
            float a0 = 0.f, a1 = 0.f, a2 = 0.f, a3 = 0.f;
#pragma unroll
            for (int j = 0; j < 32; j += 4) {
                float4 q = *(const float4*)(xr + j);
                a0 = fmaf(wr[j],   q.x, a0);
                a1 = fmaf(wr[j+1], q.y, a1);
                a2 = fmaf(wr[j+2], q.z, a2);
                a3 = fmaf(wr[j+3], q.w, a3);
            }
            acc[pi] += (a0 + a1) + (a2 + a3);
        }
    }
#pragma unroll
    for (int pi = 0; pi < PBLK; ++pi) out[(size_t)(p0 + pi) * DM + c] = acc[pi];
}

extern "C" void kernel_launch(void* const* d_in, const int* in_sizes, int n_in,
                              void* d_out, int out_size, void* d_ws, size_t ws_size,
                              hipStream_t stream) {
    const float* x      = (const float*)d_in[0];
    const float* w_in   = (const float*)d_in[1];
    const float* conv_w = (const float*)d_in[2];
    const float* conv_b = (const float*)d_in[3];
    const float* xpw    = (const float*)d_in[4];
    const float* dtw    = (const float*)d_in[5];
    const float* dtb    = (const float*)d_in[6];
    const float* A_logs = (const float*)d_in[7];
    const float* Dsv    = (const float*)d_in[8];
    const float* gamma  = (const float*)d_in[9];
    const float* beta   = (const float*)d_in[10];
    const float* wo     = (const float*)d_in[11];
    float* out = (float*)d_out;

    float* ws = (float*)d_ws;
    float* xp = ws;                                   // NPOS*192
    float* zs = xp + (size_t)NPOS * DE;               // NPOS*192
    float* xc = zs + (size_t)NPOS * DE;               // NPOS*192
    float* P  = xc + (size_t)NPOS * DE;               // NPOS*76
    float* yb = P  + (size_t)NPOS * (2 * NC);         // NPOS*384
    float* gated = xp;                                // reuse xp (dead after conv)

    k_inproj <<<(384 * (NPOS / PBLK)) / 256, 256, 0, stream>>>(x, w_in, xp, zs);
    k_conv   <<<(NPOS * 48) / 256,            256, 0, stream>>>(xp, conv_w, conv_b, xc);
    k_xproj  <<<(2 * NC * (NPOS / PBLK)) / 256, 256, 0, stream>>>(xc, xpw, P);
    k_scan   <<<Bb * Ww * 2, 192, 0, stream>>>(xc, P, dtw, dtb, A_logs, Dsv, yb);
    k_lngate <<<NPOS / 4, 256, 0, stream>>>(yb, zs, gamma, beta, gated);
    k_outproj<<<(DM * (NPOS / PBLK)) / 256,   256, 0, stream>>>(gated, wo, out);
}

// Round 3
// 282.944 us; speedup vs baseline: 2.3204x; 2.3204x over previous
//
#include <hip/hip_runtime.h>
#include <math.h>

// Problem constants
#define Bb 2
#define Hh 128
#define Ww 128
#define DM 96
#define DE 192
#define Ns 16
#define Rr 6
#define NPOS (Bb*Hh*Ww)          // 32768
#define NC 38                    // R + 2N per direction

__device__ __forceinline__ float silu_f(float v) {
    return v / (1.f + __expf(-v));
}

// ---------------------------------------------------------------------------
// Tiled fp32 GEMM: C[M x N_TOT] = A[M x K_TOT] * B[N_TOT x K_TOT]^T
// BM=128, BN=64, BK=32, 256 threads, 8x4 micro-tile.
// A in LDS row-major [128][32], float4-chunk XOR swizzle (row>>2)&7.
// B in LDS k-major  [32][64], n-chunk XOR swizzle (k>>2)&7 (conflict-free
// transpose staging + ds_read_b128 inner reads).
// SPLIT_SILU: in_proj epilogue (cols 0..191 -> O0, 192..383 -> silu -> O1,
// both row-stride 192). Otherwise masked float4 write to O0, stride N_TOT.
// ---------------------------------------------------------------------------
template<int K_TOT, int N_TOT, bool SPLIT_SILU>
__global__ __launch_bounds__(256) void k_gemm(const float* __restrict__ A,
                                              const float* __restrict__ Bw,
                                              float* __restrict__ O0,
                                              float* __restrict__ O1) {
    __shared__ float As[128 * 32];
    __shared__ float Bs[32 * 64];
    const int NB = (N_TOT + 63) / 64;
    const int tid = threadIdx.x;
    const int p0 = (blockIdx.x / NB) * 128;
    const int n0 = (blockIdx.x % NB) * 64;
    const int tm = tid >> 4;          // 0..15, owns rows 8tm..8tm+7
    const int tn = tid & 15;          // 0..15, owns cols 4tn..4tn+3

    float acc[8][4];
#pragma unroll
    for (int i = 0; i < 8; ++i)
#pragma unroll
        for (int j = 0; j < 4; ++j) acc[i][j] = 0.f;

    for (int kt = 0; kt < K_TOT; kt += 32) {
        // ---- stage A tile: 128x32, 4 float4 per thread, coalesced ----
#pragma unroll
        for (int i = 0; i < 4; ++i) {
            int f = tid + i * 256;          // float4 index, 0..1023
            int row = f >> 3;               // 8 float4 per row
            int c4  = f & 7;
            float4 v = *(const float4*)(A + (size_t)(p0 + row) * K_TOT + kt + 4 * c4);
            int sw = c4 ^ ((row >> 2) & 7);
            *(float4*)(As + row * 32 + 4 * sw) = v;
        }
        // ---- stage B tile: transpose to k-major [32][64], swizzled n ----
#pragma unroll
        for (int i = 0; i < 2; ++i) {
            int f = tid + i * 256;          // 0..511
            int n  = f >> 3;                // 0..63
            int c4 = f & 7;                 // k-chunk
            int gn = n0 + n;
            float4 v = make_float4(0.f, 0.f, 0.f, 0.f);
            if (gn < N_TOT)
                v = *(const float4*)(Bw + (size_t)gn * K_TOT + kt + 4 * c4);
            int nsw = 4 * ((n >> 2) ^ (c4 & 7)) + (n & 3);
            Bs[(4 * c4 + 0) * 64 + nsw] = v.x;
            Bs[(4 * c4 + 1) * 64 + nsw] = v.y;
            Bs[(4 * c4 + 2) * 64 + nsw] = v.z;
            Bs[(4 * c4 + 3) * 64 + nsw] = v.w;
        }
        __syncthreads();

        // ---- inner: 8 kk-groups of K=4 ----
#pragma unroll
        for (int kk = 0; kk < 8; ++kk) {
            float bs_[4][4];
            {
                int bbase = (4 * kk) * 64 + 4 * (tn ^ (kk & 7));
#pragma unroll
                for (int q = 0; q < 4; ++q) {
                    float4 t = *(const float4*)(Bs + bbase + q * 64);
                    bs_[q][0] = t.x; bs_[q][1] = t.y; bs_[q][2] = t.z; bs_[q][3] = t.w;
                }
            }
#pragma unroll
            for (int i = 0; i < 8; ++i) {
                int row = tm * 8 + i;
                float4 av = *(const float4*)(As + row * 32 + 4 * (kk ^ ((row >> 2) & 7)));
                float aq[4] = {av.x, av.y, av.z, av.w};
#pragma unroll
                for (int q = 0; q < 4; ++q)
#pragma unroll
                    for (int j = 0; j < 4; ++j)
                        acc[i][j] = fmaf(aq[q], bs_[q][j], acc[i][j]);
            }
        }
        __syncthreads();
    }

    // ---- epilogue ----
    if (SPLIT_SILU) {
        bool second = (n0 >= DE);
        float* dst = second ? O1 : O0;
        int cbase = (second ? n0 - DE : n0) + 4 * tn;
#pragma unroll
        for (int i = 0; i < 8; ++i) {
            int p = p0 + tm * 8 + i;
            float4 v;
            if (second) {
                v.x = silu_f(acc[i][0]); v.y = silu_f(acc[i][1]);
                v.z = silu_f(acc[i][2]); v.w = silu_f(acc[i][3]);
            } else {
                v.x = acc[i][0]; v.y = acc[i][1]; v.z = acc[i][2]; v.w = acc[i][3];
            }
            *(float4*)(dst + (size_t)p * DE + cbase) = v;
        }
    } else {
        int c = n0 + 4 * tn;
        if (c + 3 < N_TOT) {
#pragma unroll
            for (int i = 0; i < 8; ++i) {
                int p = p0 + tm * 8 + i;
                float4 v;
                v.x = acc[i][0]; v.y = acc[i][1]; v.z = acc[i][2]; v.w = acc[i][3];
                *(float4*)(O0 + (size_t)p * N_TOT + c) = v;
            }
        }
    }
}

// K2: depthwise 3x3 conv (pad 1) + bias + silu, channel-last layout.
__global__ __launch_bounds__(256) void k_conv(const float* __restrict__ xp,
                                              const float* __restrict__ cw,   // (192,9)
                                              const float* __restrict__ cb,
                                              float* __restrict__ xc) {
    int t = blockIdx.x * 256 + threadIdx.x;          // NPOS * 48
    int dq  = t % 48;
    int pos = t / 48;
    int ww = pos % Ww;
    int hh = (pos / Ww) % Hh;
    int bb = pos / (Hh * Ww);
    int d0 = dq * 4;
    float wgt[4][9];
#pragma unroll
    for (int cc = 0; cc < 4; ++cc)
#pragma unroll
        for (int i = 0; i < 9; ++i) wgt[cc][i] = cw[(size_t)(d0 + cc) * 9 + i];
    float a0 = 0.f, a1 = 0.f, a2 = 0.f, a3 = 0.f;
#pragma unroll
    for (int kh = 0; kh < 3; ++kh) {
        int h2 = hh + kh - 1;
        if (h2 < 0 || h2 >= Hh) continue;
#pragma unroll
        for (int kw = 0; kw < 3; ++kw) {
            int w2 = ww + kw - 1;
            if (w2 < 0 || w2 >= Ww) continue;
            const float4 q = *(const float4*)(xp + ((size_t)((bb * Hh + h2) * Ww + w2)) * DE + d0);
            int i = kh * 3 + kw;
            a0 = fmaf(wgt[0][i], q.x, a0);
            a1 = fmaf(wgt[1][i], q.y, a1);
            a2 = fmaf(wgt[2][i], q.z, a2);
            a3 = fmaf(wgt[3][i], q.w, a3);
        }
    }
    float4 r;
    r.x = silu_f(a0 + cb[d0]);
    r.y = silu_f(a1 + cb[d0+1]);
    r.z = silu_f(a2 + cb[d0+2]);
    r.w = silu_f(a3 + cb[d0+3]);
    *(float4*)(xc + (size_t)pos * DE + d0) = r;
}

// K4: selective scan. One block per (b,w,k): 512 blocks x 192 threads.
__global__ __launch_bounds__(192) void k_scan(const float* __restrict__ xc,
                                              const float* __restrict__ P,
                                              const float* __restrict__ dtw,   // (2,192,6)
                                              const float* __restrict__ dtb,   // (2,192)
                                              const float* __restrict__ A_logs,// (384,16)
                                              const float* __restrict__ Ds,
                                              float* __restrict__ yb) {        // (pos,2,192)
    int blk = blockIdx.x;
    int k  = blk & 1;
    int bw = blk >> 1;
    int ww = bw % Ww, bb = bw / Ww;
    int d  = threadIdx.x;
    int kd = k * DE + d;

    float As_[Ns];
#pragma unroll
    for (int n = 0; n < Ns; ++n) As_[n] = -__expf(A_logs[(size_t)kd * Ns + n]);
    float wdt[Rr];
#pragma unroll
    for (int r = 0; r < Rr; ++r) wdt[r] = dtw[(size_t)kd * Rr + r];
    float bias = dtb[kd];
    float Dv   = Ds[kd];

    float hst[Ns];
#pragma unroll
    for (int n = 0; n < Ns; ++n) hst[n] = 0.f;

    for (int l = 0; l < Hh; ++l) {
        int hh = k ? (Hh - 1 - l) : l;
        size_t pos = (size_t)((bb * Hh + hh) * Ww + ww);
        float u = xc[pos * DE + d];
        const float* pr = P + pos * (2 * NC) + k * NC;
        float dtr = bias;
#pragma unroll
        for (int r = 0; r < Rr; ++r) dtr = fmaf(wdt[r], pr[r], dtr);
        float delta = (dtr > 20.f) ? dtr : log1pf(__expf(dtr));
        float du = delta * u;
        float y = 0.f;
#pragma unroll
        for (int n = 0; n < Ns; ++n) {
            float dA = __expf(delta * As_[n]);
            hst[n] = fmaf(dA, hst[n], du * pr[Rr + n]);
            y = fmaf(hst[n], pr[Rr + Ns + n], y);
        }
        yb[(pos * 2 + k) * DE + d] = y + Dv * u;
    }
}

// K5: merge directions + LayerNorm(192) + gate with silu(z). Wave per position.
__global__ __launch_bounds__(256) void k_lngate(const float* __restrict__ yb,
                                                const float* __restrict__ zs,
                                                const float* __restrict__ gamma,
                                                const float* __restrict__ beta,
                                                float* __restrict__ gated) {
    int wv   = threadIdx.x >> 6;
    int lane = threadIdx.x & 63;
    size_t pos = (size_t)blockIdx.x * 4 + wv;
    const float* yr = yb + pos * (2 * DE);
    float v[3];
#pragma unroll
    for (int i = 0; i < 3; ++i) {
        int dd = lane + 64 * i;
        v[i] = yr[dd] + yr[DE + dd];
    }
    float s  = v[0] + v[1] + v[2];
    float s2 = v[0]*v[0] + v[1]*v[1] + v[2]*v[2];
#pragma unroll
    for (int off = 32; off; off >>= 1) {
        s  += __shfl_xor(s, off);
        s2 += __shfl_xor(s2, off);
    }
    float mu   = s * (1.f / DE);
    float var  = s2 * (1.f / DE) - mu * mu;
    float rstd = rsqrtf(var + 1e-5f);
#pragma unroll
    for (int i = 0; i < 3; ++i) {
        int dd = lane + 64 * i;
        float g = (v[i] - mu) * rstd * gamma[dd] + beta[dd];
        gated[pos * DE + dd] = g * zs[pos * DE + dd];
    }
}

extern "C" void kernel_launch(void* const* d_in, const int* in_sizes, int n_in,
                              void* d_out, int out_size, void* d_ws, size_t ws_size,
                              hipStream_t stream) {
    const float* x      = (const float*)d_in[0];
    const float* w_in   = (const float*)d_in[1];
    const float* conv_w = (const float*)d_in[2];
    const float* conv_b = (const float*)d_in[3];
    const float* xpw    = (const float*)d_in[4];
    const float* dtw    = (const float*)d_in[5];
    const float* dtb    = (const float*)d_in[6];
    const float* A_logs = (const float*)d_in[7];
    const float* Dsv    = (const float*)d_in[8];
    const float* gamma  = (const float*)d_in[9];
    const float* beta   = (const float*)d_in[10];
    const float* wo     = (const float*)d_in[11];
    float* out = (float*)d_out;

    float* ws = (float*)d_ws;
    float* xp = ws;                                   // NPOS*192
    float* zs = xp + (size_t)NPOS * DE;               // NPOS*192
    float* xc = zs + (size_t)NPOS * DE;               // NPOS*192
    float* P  = xc + (size_t)NPOS * DE;               // NPOS*76
    float* yb = P  + (size_t)NPOS * (2 * NC);         // NPOS*384
    float* gated = xp;                                // reuse xp (dead after conv)

    // in_proj: M=32768, N=384, K=96
    k_gemm<96, 384, true><<<(NPOS / 128) * 6, 256, 0, stream>>>(x, w_in, xp, zs);
    k_conv<<<(NPOS * 48) / 256, 256, 0, stream>>>(xp, conv_w, conv_b, xc);
    // x_proj: M=32768, N=76, K=192
    k_gemm<192, 76, false><<<(NPOS / 128) * 2, 256, 0, stream>>>(xc, xpw, P, nullptr);
    k_scan<<<Bb * Ww * 2, 192, 0, stream>>>(xc, P, dtw, dtb, A_logs, Dsv, yb);
    k_lngate<<<NPOS / 4, 256, 0, stream>>>(yb, zs, gamma, beta, gated);
    // out_proj: M=32768, N=96, K=192
    k_gemm<192, 96, false><<<(NPOS / 128) * 2, 256, 0, stream>>>(gated, wo, out, nullptr);
}

// Round 4
// 282.628 us; speedup vs baseline: 2.3230x; 1.0011x over previous
//
#include <hip/hip_runtime.h>
#include <math.h>

// Problem constants
#define Bb 2
#define Hh 128
#define Ww 128
#define DM 96
#define DE 192
#define Ns 16
#define Rr 6
#define NPOS (Bb*Hh*Ww)          // 32768
#define NC 38                    // R + 2N per direction

__device__ __forceinline__ float silu_f(float v) {
    return v / (1.f + __expf(-v));
}

// ---------------------------------------------------------------------------
// Tiled fp32 GEMM: C[M x N_TOT] = A[M x K_TOT] * B[N_TOT x K_TOT]^T
// BM=128, BN=64, BK=32, 256 threads, 8x4 micro-tile.
// A in LDS row-major [128][32], float4-chunk XOR swizzle (row>>2)&7.
// B in LDS k-major  [32][64], n-chunk XOR swizzle (k>>2)&7 (conflict-free
// transpose staging + ds_read_b128 inner reads).
// SPLIT_SILU: in_proj epilogue (cols 0..191 -> O0, 192..383 -> silu -> O1,
// both row-stride 192). Otherwise masked float4 write to O0, stride N_TOT.
// ---------------------------------------------------------------------------
template<int K_TOT, int N_TOT, bool SPLIT_SILU>
__global__ __launch_bounds__(256) void k_gemm(const float* __restrict__ A,
                                              const float* __restrict__ Bw,
                                              float* __restrict__ O0,
                                              float* __restrict__ O1) {
    __shared__ float As[128 * 32];
    __shared__ float Bs[32 * 64];
    const int NB = (N_TOT + 63) / 64;
    const int tid = threadIdx.x;
    const int p0 = (blockIdx.x / NB) * 128;
    const int n0 = (blockIdx.x % NB) * 64;
    const int tm = tid >> 4;          // 0..15, owns rows 8tm..8tm+7
    const int tn = tid & 15;          // 0..15, owns cols 4tn..4tn+3

    float acc[8][4];
#pragma unroll
    for (int i = 0; i < 8; ++i)
#pragma unroll
        for (int j = 0; j < 4; ++j) acc[i][j] = 0.f;

    for (int kt = 0; kt < K_TOT; kt += 32) {
        // ---- stage A tile: 128x32, 4 float4 per thread, coalesced ----
#pragma unroll
        for (int i = 0; i < 4; ++i) {
            int f = tid + i * 256;          // float4 index, 0..1023
            int row = f >> 3;               // 8 float4 per row
            int c4  = f & 7;
            float4 v = *(const float4*)(A + (size_t)(p0 + row) * K_TOT + kt + 4 * c4);
            int sw = c4 ^ ((row >> 2) & 7);
            *(float4*)(As + row * 32 + 4 * sw) = v;
        }
        // ---- stage B tile: transpose to k-major [32][64], swizzled n ----
#pragma unroll
        for (int i = 0; i < 2; ++i) {
            int f = tid + i * 256;          // 0..511
            int n  = f >> 3;                // 0..63
            int c4 = f & 7;                 // k-chunk
            int gn = n0 + n;
            float4 v = make_float4(0.f, 0.f, 0.f, 0.f);
            if (gn < N_TOT)
                v = *(const float4*)(Bw + (size_t)gn * K_TOT + kt + 4 * c4);
            int nsw = 4 * ((n >> 2) ^ (c4 & 7)) + (n & 3);
            Bs[(4 * c4 + 0) * 64 + nsw] = v.x;
            Bs[(4 * c4 + 1) * 64 + nsw] = v.y;
            Bs[(4 * c4 + 2) * 64 + nsw] = v.z;
            Bs[(4 * c4 + 3) * 64 + nsw] = v.w;
        }
        __syncthreads();

        // ---- inner: 8 kk-groups of K=4 ----
#pragma unroll
        for (int kk = 0; kk < 8; ++kk) {
            float bs_[4][4];
            {
                int bbase = (4 * kk) * 64 + 4 * (tn ^ (kk & 7));
#pragma unroll
                for (int q = 0; q < 4; ++q) {
                    float4 t = *(const float4*)(Bs + bbase + q * 64);
                    bs_[q][0] = t.x; bs_[q][1] = t.y; bs_[q][2] = t.z; bs_[q][3] = t.w;
                }
            }
#pragma unroll
            for (int i = 0; i < 8; ++i) {
                int row = tm * 8 + i;
                float4 av = *(const float4*)(As + row * 32 + 4 * (kk ^ ((row >> 2) & 7)));
                float aq[4] = {av.x, av.y, av.z, av.w};
#pragma unroll
                for (int q = 0; q < 4; ++q)
#pragma unroll
                    for (int j = 0; j < 4; ++j)
                        acc[i][j] = fmaf(aq[q], bs_[q][j], acc[i][j]);
            }
        }
        __syncthreads();
    }

    // ---- epilogue ----
    if (SPLIT_SILU) {
        bool second = (n0 >= DE);
        float* dst = second ? O1 : O0;
        int cbase = (second ? n0 - DE : n0) + 4 * tn;
#pragma unroll
        for (int i = 0; i < 8; ++i) {
            int p = p0 + tm * 8 + i;
            float4 v;
            if (second) {
                v.x = silu_f(acc[i][0]); v.y = silu_f(acc[i][1]);
                v.z = silu_f(acc[i][2]); v.w = silu_f(acc[i][3]);
            } else {
                v.x = acc[i][0]; v.y = acc[i][1]; v.z = acc[i][2]; v.w = acc[i][3];
            }
            *(float4*)(dst + (size_t)p * DE + cbase) = v;
        }
    } else {
        int c = n0 + 4 * tn;
        if (c + 3 < N_TOT) {
#pragma unroll
            for (int i = 0; i < 8; ++i) {
                int p = p0 + tm * 8 + i;
                float4 v;
                v.x = acc[i][0]; v.y = acc[i][1]; v.z = acc[i][2]; v.w = acc[i][3];
                *(float4*)(O0 + (size_t)p * N_TOT + c) = v;
            }
        }
    }
}

// K2: depthwise 3x3 conv (pad 1) + bias + silu, channel-last layout.
__global__ __launch_bounds__(256) void k_conv(const float* __restrict__ xp,
                                              const float* __restrict__ cw,   // (192,9)
                                              const float* __restrict__ cb,
                                              float* __restrict__ xc) {
    int t = blockIdx.x * 256 + threadIdx.x;          // NPOS * 48
    int dq  = t % 48;
    int pos = t / 48;
    int ww = pos % Ww;
    int hh = (pos / Ww) % Hh;
    int bb = pos / (Hh * Ww);
    int d0 = dq * 4;
    float wgt[4][9];
#pragma unroll
    for (int cc = 0; cc < 4; ++cc)
#pragma unroll
        for (int i = 0; i < 9; ++i) wgt[cc][i] = cw[(size_t)(d0 + cc) * 9 + i];
    float a0 = 0.f, a1 = 0.f, a2 = 0.f, a3 = 0.f;
#pragma unroll
    for (int kh = 0; kh < 3; ++kh) {
        int h2 = hh + kh - 1;
        if (h2 < 0 || h2 >= Hh) continue;
#pragma unroll
        for (int kw = 0; kw < 3; ++kw) {
            int w2 = ww + kw - 1;
            if (w2 < 0 || w2 >= Ww) continue;
            const float4 q = *(const float4*)(xp + ((size_t)((bb * Hh + h2) * Ww + w2)) * DE + d0);
            int i = kh * 3 + kw;
            a0 = fmaf(wgt[0][i], q.x, a0);
            a1 = fmaf(wgt[1][i], q.y, a1);
            a2 = fmaf(wgt[2][i], q.z, a2);
            a3 = fmaf(wgt[3][i], q.w, a3);
        }
    }
    float4 r;
    r.x = silu_f(a0 + cb[d0]);
    r.y = silu_f(a1 + cb[d0+1]);
    r.z = silu_f(a2 + cb[d0+2]);
    r.w = silu_f(a3 + cb[d0+3]);
    *(float4*)(xc + (size_t)pos * DE + d0) = r;
}

// K4: selective scan. One block per (b,w,k): 512 blocks x 192 threads.
__global__ __launch_bounds__(192) void k_scan(const float* __restrict__ xc,
                                              const float* __restrict__ P,
                                              const float* __restrict__ dtw,   // (2,192,6)
                                              const float* __restrict__ dtb,   // (2,192)
                                              const float* __restrict__ A_logs,// (384,16)
                                              const float* __restrict__ Ds,
                                              float* __restrict__ yb) {        // (pos,2,192)
    int blk = blockIdx.x;
    int k  = blk & 1;
    int bw = blk >> 1;
    int ww = bw % Ww, bb = bw / Ww;
    int d  = threadIdx.x;
    int kd = k * DE + d;

    float As_[Ns];
#pragma unroll
    for (int n = 0; n < Ns; ++n) As_[n] = -__expf(A_logs[(size_t)kd * Ns + n]);
    float wdt[Rr];
#pragma unroll
    for (int r = 0; r < Rr; ++r) wdt[r] = dtw[(size_t)kd * Rr + r];
    float bias = dtb[kd];
    float Dv   = Ds[kd];

    float hst[Ns];
#pragma unroll
    for (int n = 0; n < Ns; ++n) hst[n] = 0.f;

    for (int l = 0; l < Hh; ++l) {
        int hh = k ? (Hh - 1 - l) : l;
        size_t pos = (size_t)((bb * Hh + hh) * Ww + ww);
        float u = xc[pos * DE + d];
        const float* pr = P + pos * (2 * NC) + k * NC;
        float dtr = bias;
#pragma unroll
        for (int r = 0; r < Rr; ++r) dtr = fmaf(wdt[r], pr[r], dtr);
        float delta = (dtr > 20.f) ? dtr : log1pf(__expf(dtr));
        float du = delta * u;
        float y = 0.f;
#pragma unroll
        for (int n = 0; n < Ns; ++n) {
            float dA = __expf(delta * As_[n]);
            hst[n] = fmaf(dA, hst[n], du * pr[Rr + n]);
            y = fmaf(hst[n], pr[Rr + Ns + n], y);
        }
        yb[(pos * 2 + k) * DE + d] = y + Dv * u;
    }
}

// K5: merge directions + LayerNorm(192) + gate with silu(z). Wave per position.
__global__ __launch_bounds__(256) void k_lngate(const float* __restrict__ yb,
                                                const float* __restrict__ zs,
                                                const float* __restrict__ gamma,
                                                const float* __restrict__ beta,
                                                float* __restrict__ gated) {
    int wv   = threadIdx.x >> 6;
    int lane = threadIdx.x & 63;
    size_t pos = (size_t)blockIdx.x * 4 + wv;
    const float* yr = yb + pos * (2 * DE);
    float v[3];
#pragma unroll
    for (int i = 0; i < 3; ++i) {
        int dd = lane + 64 * i;
        v[i] = yr[dd] + yr[DE + dd];
    }
    float s  = v[0] + v[1] + v[2];
    float s2 = v[0]*v[0] + v[1]*v[1] + v[2]*v[2];
#pragma unroll
    for (int off = 32; off; off >>= 1) {
        s  += __shfl_xor(s, off);
        s2 += __shfl_xor(s2, off);
    }
    float mu   = s * (1.f / DE);
    float var  = s2 * (1.f / DE) - mu * mu;
    float rstd = rsqrtf(var + 1e-5f);
#pragma unroll
    for (int i = 0; i < 3; ++i) {
        int dd = lane + 64 * i;
        float g = (v[i] - mu) * rstd * gamma[dd] + beta[dd];
        gated[pos * DE + dd] = g * zs[pos * DE + dd];
    }
}

extern "C" void kernel_launch(void* const* d_in, const int* in_sizes, int n_in,
                              void* d_out, int out_size, void* d_ws, size_t ws_size,
                              hipStream_t stream) {
    const float* x      = (const float*)d_in[0];
    const float* w_in   = (const float*)d_in[1];
    const float* conv_w = (const float*)d_in[2];
    const float* conv_b = (const float*)d_in[3];
    const float* xpw    = (const float*)d_in[4];
    const float* dtw    = (const float*)d_in[5];
    const float* dtb    = (const float*)d_in[6];
    const float* A_logs = (const float*)d_in[7];
    const float* Dsv    = (const float*)d_in[8];
    const float* gamma  = (const float*)d_in[9];
    const float* beta   = (const float*)d_in[10];
    const float* wo     = (const float*)d_in[11];
    float* out = (float*)d_out;

    float* ws = (float*)d_ws;
    float* xp = ws;                                   // NPOS*192
    float* zs = xp + (size_t)NPOS * DE;               // NPOS*192
    float* xc = zs + (size_t)NPOS * DE;               // NPOS*192
    float* P  = xc + (size_t)NPOS * DE;               // NPOS*76
    float* yb = P  + (size_t)NPOS * (2 * NC);         // NPOS*384
    float* gated = xp;                                // reuse xp (dead after conv)

    // in_proj: M=32768, N=384, K=96
    k_gemm<96, 384, true><<<(NPOS / 128) * 6, 256, 0, stream>>>(x, w_in, xp, zs);
    k_conv<<<(NPOS * 48) / 256, 256, 0, stream>>>(xp, conv_w, conv_b, xc);
    // x_proj: M=32768, N=76, K=192
    k_gemm<192, 76, false><<<(NPOS / 128) * 2, 256, 0, stream>>>(xc, xpw, P, nullptr);
    k_scan<<<Bb * Ww * 2, 192, 0, stream>>>(xc, P, dtw, dtb, A_logs, Dsv, yb);
    k_lngate<<<NPOS / 4, 256, 0, stream>>>(yb, zs, gamma, beta, gated);
    // out_proj: M=32768, N=96, K=192
    k_gemm<192, 96, false><<<(NPOS / 128) * 2, 256, 0, stream>>>(gated, wo, out, nullptr);
}